// Round 1
// baseline (2211.760 us; speedup 1.0000x reference)
//
#include <hip/hip_runtime.h>
#include <stdint.h>

#define NB 16      // batch
#define TT 4096    // seq len
#define DD 512     // dim
#define CC 32      // chunk size
#define MM 64      // mem slots
#define NCH 128    // number of chunks

__device__ __forceinline__ float wredsum(float v){
#pragma unroll
  for (int o = 32; o > 0; o >>= 1) v += __shfl_xor(v, o);
  return v;
}
__device__ __forceinline__ float wredmax(float v){
#pragma unroll
  for (int o = 32; o > 0; o >>= 1) v = fmaxf(v, __shfl_xor(v, o));
  return v;
}

// One persistent block per batch. mem held transposed in LDS: memT[k][m].
// Cross-batch coupling (entropy scalar) exchanged via device-scope atomics in
// the tail of d_out (generation-tagged 64-bit words; robust to 0x00/0xAA init).
__global__ __launch_bounds__(1024)
void membank_kernel(const float* __restrict__ x,
                    const float* __restrict__ mem_init,
                    float* __restrict__ out)
{
  __shared__ float memT[DD][MM];        // 128 KiB  [k][m]
  __shared__ float red[3][CC][MM];      // 24 KiB   GEMM partials / logits / probs
  __shared__ float s_newm[DD];          // maxpooled chunk
  __shared__ float s_score[MM];
  __shared__ float s_sc[MM];            // m_score state
  __shared__ float s_fr[MM];            // m_freq state
  __shared__ float s_nm2part[8];
  __shared__ float s_entvals[NB];
  __shared__ int   s_take1, s_idx1, s_idx2;

  // phase-disjoint aliases inside red[1] (dead after logits combine)
  float* rnp = &red[1][0][0];           // 8x64 norm partials
  float* rdp = &red[1][8][0];           // 8x64 dot partials

  const int tid  = threadIdx.x;
  const int lane = tid & 63;
  const int w    = tid >> 6;
  const int b    = blockIdx.x;
  const int wu   = __builtin_amdgcn_readfirstlane(w);   // force SGPR: enables s_load addressing
  const int gu   = wu >> 2;   // token group (8 tokens)
  const int hu   = wu & 3;    // k-range (128 k)

  // ---- init: load mem_init (transposed) + zero states ----
  {
    const int m  = tid >> 4;
    const int kc = tid & 15;
    const float* src = mem_init + ((size_t)b*MM + m)*DD;
#pragma unroll 4
    for (int i = 0; i < 32; ++i){ const int k = kc + i*16; memT[k][m] = src[k]; }
  }
  if (tid < MM){ s_sc[tid] = 0.0f; s_fr[tid] = 0.0f; }
  __syncthreads();

  unsigned long long* ctl = (unsigned long long*)(out + (size_t)NB*MM*DD) - 32; // last 256 B of d_out
  const float inv_sqrt_d = 1.0f / sqrtf((float)DD);

  for (int t = 0; t < NCH; ++t){
    const float* xb = x + ((size_t)b*TT + (size_t)t*CC)*DD;

    // ---- P0: new_m = maxpool over chunk + ||new_m||^2 partials (waves 0..7) ----
    if (wu < 8){
      const int k = wu*64 + lane;
      float v = -INFINITY;
#pragma unroll
      for (int c = 0; c < CC; ++c) v = fmaxf(v, xb[(size_t)c*DD + k]);
      s_newm[k] = v;
      const float p = wredsum(v*v);
      if (lane == 0) s_nm2part[wu] = p;
    }

    // ---- P1: logits GEMM. wave (gu,hu): tokens [gu*8,+8) x k in [hu*128,+128), slot = lane ----
    {
      const float* xg = xb + (size_t)gu*8*DD;
      float acc[8] = {0,0,0,0,0,0,0,0};
      const int k0 = hu*128;
#pragma unroll 4
      for (int kk = 0; kk < 128; ++kk){
        const int k = k0 + kk;
        const float mv = memT[k][lane];
#pragma unroll
        for (int j = 0; j < 8; ++j)
          acc[j] = fmaf(xg[(size_t)j*DD + k], mv, acc[j]);
      }
      if (hu != 0){
#pragma unroll
        for (int j = 0; j < 8; ++j) red[hu-1][gu*8+j][lane] = acc[j];
      }
      __syncthreads();
      if (hu == 0){
#pragma unroll
        for (int j = 0; j < 8; ++j){
          const int c = gu*8 + j;
          float l = acc[j] + red[0][c][lane];
          l += red[1][c][lane];
          l += red[2][c][lane];
          red[0][c][lane] = l * inv_sqrt_d;
        }
      }
      __syncthreads();
    }

    // ---- P2: row softmax over m (each wave: 2 rows) ----
    {
#pragma unroll
      for (int r = 0; r < 2; ++r){
        const int c = w*2 + r;
        const float v  = red[0][c][lane];
        const float mx = wredmax(v);
        const float e  = expf(v - mx);
        const float s  = wredsum(e);
        red[0][c][lane] = e / s;
      }
    }
    __syncthreads();

    // ---- P3: wave0: score+entropy, publish, spin for all 16; waves 8..15: norm/dot partials ----
    if (wu == 0){
      float s = 0.0f;
      for (int c = 0; c < CC; ++c) s += red[0][c][lane];
      s *= (1.0f/32.0f);
      s_score[lane] = s;
      const float ent = wredsum(-log2f(s + 1e-10f) * s);
      if (lane == 0){
        const unsigned long long v =
            ((unsigned long long)(unsigned)(t+1) << 32) |
            (unsigned long long)__float_as_uint(ent);
        __hip_atomic_store(&ctl[b*2 + (t&1)], v, __ATOMIC_RELEASE, __HIP_MEMORY_SCOPE_AGENT);
      }
      if (lane < NB){
        unsigned long long vv;
        do {
          vv = __hip_atomic_load(&ctl[lane*2 + (t&1)], __ATOMIC_ACQUIRE, __HIP_MEMORY_SCOPE_AGENT);
        } while ((unsigned)(vv >> 32) != (unsigned)(t+1));
        s_entvals[lane] = __uint_as_float((unsigned)vv);
      }
    } else if (wu >= 8){
      const int idx = wu - 8;
      float an = 0.0f, ad = 0.0f;
      const int k0 = idx*64;
#pragma unroll 4
      for (int kk = 0; kk < 64; ++kk){
        const int k = k0 + kk;
        const float mv = memT[k][lane];
        const float nv = s_newm[k];
        an = fmaf(mv, mv, an);
        ad = fmaf(nv, mv, ad);
      }
      rnp[idx*MM + lane] = an;
      rdp[idx*MM + lane] = ad;
    }
    __syncthreads();

    // ---- P4: decision + argmax(sim) + argmin(avg score) ----
    if (wu == 0){
      if (lane == 0){
        float es = 0.0f;
        for (int i = 0; i < NB; ++i) es += s_entvals[i];
        s_take1 = ((es * (1.0f/16.0f)) > 3.0f) ? 1 : 0;   // threshold = 0.5*log2(64+1e-10) == 3.0f in fp32
      }
    } else if (wu == 1){
      float n2 = 0.0f, dt = 0.0f, nm2 = 0.0f;
#pragma unroll
      for (int i = 0; i < 8; ++i){ n2 += rnp[i*MM+lane]; dt += rdp[i*MM+lane]; }
#pragma unroll
      for (int i = 0; i < 8; ++i) nm2 += s_nm2part[i];
      float sim = dt / (sqrtf(nm2 + 1e-8f) * sqrtf(n2 + 1e-8f));
      int idx = lane;
#pragma unroll
      for (int o = 32; o > 0; o >>= 1){
        const float ov = __shfl_xor(sim, o);
        const int   oi = __shfl_xor(idx, o);
        if (ov > sim || (ov == sim && oi < idx)){ sim = ov; idx = oi; }  // first-occurrence argmax
      }
      if (lane == 0) s_idx2 = idx;
    } else if (wu == 2){
      float q = (s_sc[lane] + s_score[lane]) / (s_fr[lane] + 1.0f);
      int idx = lane;
#pragma unroll
      for (int o = 32; o > 0; o >>= 1){
        const float ov = __shfl_xor(q, o);
        const int   oi = __shfl_xor(idx, o);
        if (ov < q || (ov == q && oi < idx)){ q = ov; idx = oi; }        // first-occurrence argmin
      }
      if (lane == 0) s_idx1 = idx;
    }
    __syncthreads();

    // ---- P5: apply the selected update ----
    if (s_take1){
      if (wu < 8){
        const int k = wu*64 + lane;
        memT[k][s_idx1] = s_newm[k];
      } else if (wu == 8){
        float ns = s_sc[lane] + s_score[lane];
        float nf = s_fr[lane] + 1.0f;
        if (lane == s_idx1){ ns = 0.0f; nf = 1.0f; }
        s_sc[lane] = ns; s_fr[lane] = nf;
      }
    } else {
      if (wu < 8){
        const int k = wu*64 + lane;
        const float mv = memT[k][s_idx2];
        memT[k][s_idx2] = mv + (0.7f*s_newm[k] - 0.7f*mv);
      }
      // m_score / m_freq unchanged on path 2
    }
    __syncthreads();
  }

  // ---- done-handshake: nobody overwrites the ctl region (block 15's output rows)
  //      until every block has consumed the t=127 entropies ----
  if (tid == 0){
    __hip_atomic_store(&ctl[b*2], (unsigned long long)0xD00Du << 32,
                       __ATOMIC_RELEASE, __HIP_MEMORY_SCOPE_AGENT);
  }
  if (tid < NB){
    unsigned long long vv;
    do {
      vv = __hip_atomic_load(&ctl[tid*2], __ATOMIC_ACQUIRE, __HIP_MEMORY_SCOPE_AGENT);
    } while ((unsigned)(vv >> 32) != 0xD00Du);
  }
  __syncthreads();

  // ---- write output: out[b][m][k] = memT[k][m] ----
  {
    const int m  = tid >> 4;
    const int kc = tid & 15;
    float* dst = out + ((size_t)b*MM + m)*DD;
#pragma unroll 4
    for (int i = 0; i < 32; ++i){ const int k = kc + i*16; dst[k] = memT[k][m]; }
  }
}

extern "C" void kernel_launch(void* const* d_in, const int* in_sizes, int n_in,
                              void* d_out, int out_size, void* d_ws, size_t ws_size,
                              hipStream_t stream)
{
  const float* x  = (const float*)d_in[0];
  const float* mi = (const float*)d_in[1];
  float* out = (float*)d_out;
  hipLaunchKernelGGL(membank_kernel, dim3(NB), dim3(1024), 0, stream, x, mi, out);
}

// Round 2
// 1022.983 us; speedup vs baseline: 2.1621x; 2.1621x over previous
//
#include <hip/hip_runtime.h>
#include <stdint.h>

#define NB 16      // batch
#define TT 4096    // seq len
#define DD 512     // dim
#define CC 32      // chunk size
#define MM 64      // mem slots
#define NCH 128    // number of chunks
#define NSRC 192   // 64 init + 128 newm sources
#define ROWW 36    // Gx row stride floats: 32 logits + 1 NN + 3 pad
#define TOTROWS 16320  // sum_{t=0}^{127} (64+t)

// ws float-offsets
#define WS_NEWM 0
#define WS_NN2  (NB*NCH*DD)                 // 1,048,576
#define WS_GX   (WS_NN2 + NB*NCH)           // 1,050,624
#define WS_TOTAL_FLOATS (WS_GX + (size_t)NB*TOTROWS*ROWW)   // 10,450,944
#define WS_TOTAL_BYTES  (WS_TOTAL_FLOATS*4) // 41,803,776

__device__ __forceinline__ float wredsum(float v){
#pragma unroll
  for (int o = 32; o > 0; o >>= 1) v += __shfl_xor(v, o);
  return v;
}
__device__ __forceinline__ float wredmax(float v){
#pragma unroll
  for (int o = 32; o > 0; o >>= 1) v = fmaxf(v, __shfl_xor(v, o));
  return v;
}

// ======================= K1: maxpool new_m + ||new_m||^2 =======================
__global__ __launch_bounds__(256)
void k1_newm(const float* __restrict__ x, float* __restrict__ ws)
{
  __shared__ float part[4];
  const int bid = blockIdx.x;
  const int b = bid >> 7, t = bid & 127;
  const int tid = threadIdx.x;
  const float* xb = x + ((size_t)b*TT + (size_t)t*CC)*DD;
  const int k0 = tid*2;
  float v0 = -INFINITY, v1 = -INFINITY;
#pragma unroll
  for (int c = 0; c < CC; ++c){
    const float2 xv = *(const float2*)(xb + (size_t)c*DD + k0);
    v0 = fmaxf(v0, xv.x); v1 = fmaxf(v1, xv.y);
  }
  float* nm = ws + WS_NEWM + ((size_t)b*NCH + t)*DD;
  nm[k0] = v0; nm[k0+1] = v1;
  float p = wredsum(v0*v0 + v1*v1);
  if ((tid & 63) == 0) part[tid >> 6] = p;
  __syncthreads();
  if (tid == 0) ws[WS_NN2 + (size_t)b*NCH + t] = part[0]+part[1]+part[2]+part[3];
}

// ======= K2: Gx[t][row][c] = (chunk_t[c] . src_row) * inv_sqrt_d; col32 = newm_t . src_row =======
// grid (b, round r in 0..2, t-group of 8). rows = 64*r + lane; valid iff row < 64+t.
__global__ __launch_bounds__(1024)
void k2_gx(const float* __restrict__ x, const float* __restrict__ mem_init,
           float* __restrict__ ws)
{
  __shared__ float VT[DD][MM];        // 128 KiB: src tile transposed [k][s]
  __shared__ float red[3][33][MM];    // partials: 32 c cols + NN col

  const int b  = blockIdx.x;
  const int r  = blockIdx.y;
  const int tg = blockIdx.z;
  if (tg*8 + 7 < 64*(r-1) + 1) return;   // whole group below first valid t

  const int tid = threadIdx.x, lane = tid & 63, w = tid >> 6;
  const int wu = __builtin_amdgcn_readfirstlane(w);
  const int gu = wu >> 2, hu = wu & 3;

  const float* newmarr = ws + WS_NEWM;
  float* gx = ws + WS_GX;

  // stage src tile (transposed)
  {
    const int m = tid >> 4, kc = tid & 15;
    const float* src = (r == 0) ? (mem_init + ((size_t)b*MM + m)*DD)
                                : (newmarr + ((size_t)b*NCH + (64*(r-1) + m))*DD);
#pragma unroll 4
    for (int i = 0; i < 32; ++i){ const int k = kc + i*16; VT[k][m] = src[k]; }
  }
  __syncthreads();

  const float inv_sqrt_d = 1.0f / sqrtf((float)DD);

  for (int tt = 0; tt < 8; ++tt){
    const int t = tg*8 + tt;
    if (t < 64*(r-1) + 1) continue;     // uniform per block

    const float* xg  = x + ((size_t)b*TT + (size_t)t*CC + gu*8)*DD;
    const float* nmv = newmarr + ((size_t)b*NCH + t)*DD;

    float acc[8] = {0,0,0,0,0,0,0,0};
    float accN = 0.0f;
    const int kb = hu*128;
    if (gu == 0){
#pragma unroll 4
      for (int kk = 0; kk < 128; ++kk){
        const int k = kb + kk;
        const float mv = VT[k][lane];
#pragma unroll
        for (int j = 0; j < 8; ++j) acc[j] = fmaf(xg[(size_t)j*DD + k], mv, acc[j]);
        accN = fmaf(nmv[k], mv, accN);
      }
    } else {
#pragma unroll 4
      for (int kk = 0; kk < 128; ++kk){
        const int k = kb + kk;
        const float mv = VT[k][lane];
#pragma unroll
        for (int j = 0; j < 8; ++j) acc[j] = fmaf(xg[(size_t)j*DD + k], mv, acc[j]);
      }
    }
    if (hu != 0){
#pragma unroll
      for (int j = 0; j < 8; ++j) red[hu-1][gu*8+j][lane] = acc[j];
      if (gu == 0) red[hu-1][32][lane] = accN;
    }
    __syncthreads();
    if (hu == 0){
      const int row = 64*r + lane;
      if (row < 64 + t){
        const size_t rowbase = (size_t)b*TOTROWS + (size_t)(64*t + (t*(t-1))/2);
        float* grow = gx + (rowbase + row)*ROWW;
#pragma unroll
        for (int j = 0; j < 8; ++j){
          const int c = gu*8 + j;
          grow[c] = (acc[j] + red[0][c][lane] + red[1][c][lane] + red[2][c][lane]) * inv_sqrt_d;
        }
        if (gu == 0)
          grow[32] = accN + red[0][32][lane] + red[1][32][lane] + red[2][32][lane];
      }
    }
    __syncthreads();
  }
}

// ======================= K3: sequential scan in coefficient space =======================
__global__ __launch_bounds__(1024)
void k3_scan(const float* __restrict__ mem_init, const float* __restrict__ ws,
             float* __restrict__ out)
{
  __shared__ float red0[CC*65];        // logits/probs [c][m] stride 65
  __shared__ float dense[MM][NSRC];    // dense coef rows (only for complex slots)
  __shared__ float s_score[MM], s_sc[MM], s_fr[MM], s_n2[MM], s_simdot[MM];
  __shared__ int   s_srcRow[MM], s_isC[MM];
  __shared__ float s_entvals[NB];
  __shared__ int   s_take1, s_idx1, s_idx2;

  const int tid  = threadIdx.x;
  const int lane = tid & 63;
  const int w    = tid >> 6;
  const int b    = blockIdx.x;
  const int wu   = __builtin_amdgcn_readfirstlane(w);

  const float* newmarr = ws + WS_NEWM;
  const float* nn2arr  = ws + WS_NN2;
  const float* gx      = ws + WS_GX;

  // init state
  if (tid < MM){ s_sc[tid] = 0.0f; s_fr[tid] = 0.0f; s_srcRow[tid] = tid; s_isC[tid] = 0; }
#pragma unroll
  for (int it = 0; it < 4; ++it){       // init norms ||mem_init[m]||^2
    const int m = wu + it*16;
    const float* src = mem_init + ((size_t)b*MM + m)*DD;
    const float4 a = *(const float4*)(src + lane*8);
    const float4 c4 = *(const float4*)(src + lane*8 + 4);
    float p = a.x*a.x + a.y*a.y + a.z*a.z + a.w*a.w
            + c4.x*c4.x + c4.y*c4.y + c4.z*c4.z + c4.w*c4.w;
    p = wredsum(p);
    if (lane == 0) s_n2[m] = p;
  }
  __syncthreads();

  unsigned long long* ctl = (unsigned long long*)(out + (size_t)NB*MM*DD) - 32;

  for (int t = 0; t < NCH; ++t){
    const float nn2_t = nn2arr[(size_t)b*NCH + t];
    const float* gxb = gx + ((size_t)b*TOTROWS + (size_t)(64*t + (t*(t-1))/2))*ROWW;

    // ---- Ph1: assemble logits [32 c][64 m] + sim-dot from Gx ----
    {
      const int m  = tid >> 4;
      const int c2 = (tid & 15)*2;
      float v0, v1;
      if (!s_isC[m]){
        const float* grow = gxb + (size_t)s_srcRow[m]*ROWW;
        v0 = grow[c2]; v1 = grow[c2+1];
        if ((tid & 15) == 0) s_simdot[m] = grow[32];
      } else {
        v0 = 0.0f; v1 = 0.0f; float sd = 0.0f;
        const int ns = 64 + t;
        for (int s = 0; s < ns; ++s){
          const float co = dense[m][s];
          if (co != 0.0f){
            const float* grow = gxb + (size_t)s*ROWW;
            v0 = fmaf(co, grow[c2],   v0);
            v1 = fmaf(co, grow[c2+1], v1);
            if ((tid & 15) == 0) sd = fmaf(co, grow[32], sd);
          }
        }
        if ((tid & 15) == 0) s_simdot[m] = sd;
      }
      red0[c2*65 + m]     = v0;
      red0[(c2+1)*65 + m] = v1;
    }
    __syncthreads();

    // ---- Ph2: softmax over m, each wave 2 rows ----
#pragma unroll
    for (int rr = 0; rr < 2; ++rr){
      const int c = w*2 + rr;
      const float v  = red0[c*65 + lane];
      const float mx = wredmax(v);
      const float e  = expf(v - mx);
      const float s  = wredsum(e);
      red0[c*65 + lane] = e / s;
    }
    __syncthreads();

    // ---- Ph3: wave0 score+entropy+publish+argmin+spin+decide; wave1 sim+argmax ----
    if (wu == 0){
      float s = 0.0f;
      for (int c = 0; c < CC; ++c) s += red0[c*65 + lane];
      s *= (1.0f/32.0f);
      s_score[lane] = s;
      const float ent = wredsum(-log2f(s + 1e-10f) * s);
      if (lane == 0){
        const unsigned long long v =
            ((unsigned long long)(unsigned)(t+1) << 32) |
            (unsigned long long)__float_as_uint(ent);
        __hip_atomic_store(&ctl[b*2 + (t&1)], v, __ATOMIC_RELEASE, __HIP_MEMORY_SCOPE_AGENT);
      }
      // argmin of avg score (first occurrence)
      {
        float q = (s_sc[lane] + s) / (s_fr[lane] + 1.0f);
        int idx = lane;
#pragma unroll
        for (int o = 32; o > 0; o >>= 1){
          const float ov = __shfl_xor(q, o);
          const int   oi = __shfl_xor(idx, o);
          if (ov < q || (ov == q && oi < idx)){ q = ov; idx = oi; }
        }
        if (lane == 0) s_idx1 = idx;
      }
      if (lane < NB){
        unsigned long long vv;
        do {
          vv = __hip_atomic_load(&ctl[lane*2 + (t&1)], __ATOMIC_ACQUIRE, __HIP_MEMORY_SCOPE_AGENT);
        } while ((unsigned)(vv >> 32) != (unsigned)(t+1));
        s_entvals[lane] = __uint_as_float((unsigned)vv);
      }
      if (lane == 0){
        float es = 0.0f;
        for (int i = 0; i < NB; ++i) es += s_entvals[i];
        s_take1 = ((es * (1.0f/16.0f)) > 3.0f) ? 1 : 0;
      }
    } else if (wu == 1){
      float sim = s_simdot[lane] / (sqrtf(nn2_t + 1e-8f) * sqrtf(s_n2[lane] + 1e-8f));
      int idx = lane;
#pragma unroll
      for (int o = 32; o > 0; o >>= 1){
        const float ov = __shfl_xor(sim, o);
        const int   oi = __shfl_xor(idx, o);
        if (ov > sim || (ov == sim && oi < idx)){ sim = ov; idx = oi; }
      }
      if (lane == 0) s_idx2 = idx;
    }
    __syncthreads();

    // ---- Ph5a: parallel part of apply ----
    if (s_take1){
      if (tid < MM){
        float ns = s_sc[tid] + s_score[tid];
        float nf = s_fr[tid] + 1.0f;
        if (tid == s_idx1){ ns = 0.0f; nf = 1.0f; }
        s_sc[tid] = ns; s_fr[tid] = nf;
      }
    } else {
      const int i = s_idx2;
      if (!s_isC[i]){
        if (tid < NSRC) dense[i][tid] = (tid == s_srcRow[i]) ? 0.3f : 0.0f;
      } else {
        if (tid < NSRC) dense[i][tid] *= 0.3f;
      }
    }
    __syncthreads();
    // ---- Ph5b: serial bookkeeping ----
    if (tid == 0){
      if (s_take1){
        const int rr = s_idx1;
        s_isC[rr] = 0; s_srcRow[rr] = 64 + t; s_n2[rr] = nn2_t;
      } else {
        const int i = s_idx2;
        dense[i][64 + t] = 0.7f;
        s_isC[i] = 1;
        s_n2[i] = 0.09f*s_n2[i] + 0.42f*s_simdot[i] + 0.49f*nn2_t;
      }
    }
    __syncthreads();
  }

  // ---- done-handshake (nobody may overwrite ctl region until all consumed t=127) ----
  if (tid == 0){
    __hip_atomic_store(&ctl[b*2], (unsigned long long)0xD00Du << 32,
                       __ATOMIC_RELEASE, __HIP_MEMORY_SCOPE_AGENT);
  }
  if (tid < NB){
    unsigned long long vv;
    do {
      vv = __hip_atomic_load(&ctl[tid*2], __ATOMIC_ACQUIRE, __HIP_MEMORY_SCOPE_AGENT);
    } while ((unsigned)(vv >> 32) != 0xD00Du);
  }
  __syncthreads();

  // ---- reconstruction: out[b][m][:] from basis vectors ----
#pragma unroll
  for (int it = 0; it < 4; ++it){
    const int m = wu + it*16;
    const int k0 = lane*8;
    float o8[8];
    if (!s_isC[m]){
      const int row = s_srcRow[m];
      const float* vec = (row < 64) ? (mem_init + ((size_t)b*MM + row)*DD)
                                    : (newmarr + ((size_t)b*NCH + (row - 64))*DD);
#pragma unroll
      for (int j = 0; j < 8; ++j) o8[j] = vec[k0 + j];
    } else {
#pragma unroll
      for (int j = 0; j < 8; ++j) o8[j] = 0.0f;
      for (int s = 0; s < NSRC; ++s){
        const float co = dense[m][s];
        if (co != 0.0f){
          const float* vec = (s < 64) ? (mem_init + ((size_t)b*MM + s)*DD)
                                      : (newmarr + ((size_t)b*NCH + (s - 64))*DD);
#pragma unroll
          for (int j = 0; j < 8; ++j) o8[j] = fmaf(co, vec[k0 + j], o8[j]);
        }
      }
    }
    float* dst = out + ((size_t)b*MM + m)*DD + k0;
#pragma unroll
    for (int j = 0; j < 8; ++j) dst[j] = o8[j];
  }
}

// ======================= v1 fallback (proven correct) =======================
__global__ __launch_bounds__(1024)
void membank_kernel(const float* __restrict__ x,
                    const float* __restrict__ mem_init,
                    float* __restrict__ out)
{
  __shared__ float memT[DD][MM];
  __shared__ float red[3][CC][MM];
  __shared__ float s_newm[DD];
  __shared__ float s_score[MM];
  __shared__ float s_sc[MM];
  __shared__ float s_fr[MM];
  __shared__ float s_nm2part[8];
  __shared__ float s_entvals[NB];
  __shared__ int   s_take1, s_idx1, s_idx2;

  float* rnp = &red[1][0][0];
  float* rdp = &red[1][8][0];

  const int tid  = threadIdx.x;
  const int lane = tid & 63;
  const int w    = tid >> 6;
  const int b    = blockIdx.x;
  const int wu   = __builtin_amdgcn_readfirstlane(w);
  const int gu   = wu >> 2;
  const int hu   = wu & 3;

  {
    const int m  = tid >> 4;
    const int kc = tid & 15;
    const float* src = mem_init + ((size_t)b*MM + m)*DD;
#pragma unroll 4
    for (int i = 0; i < 32; ++i){ const int k = kc + i*16; memT[k][m] = src[k]; }
  }
  if (tid < MM){ s_sc[tid] = 0.0f; s_fr[tid] = 0.0f; }
  __syncthreads();

  unsigned long long* ctl = (unsigned long long*)(out + (size_t)NB*MM*DD) - 32;
  const float inv_sqrt_d = 1.0f / sqrtf((float)DD);

  for (int t = 0; t < NCH; ++t){
    const float* xb = x + ((size_t)b*TT + (size_t)t*CC)*DD;
    if (wu < 8){
      const int k = wu*64 + lane;
      float v = -INFINITY;
#pragma unroll
      for (int c = 0; c < CC; ++c) v = fmaxf(v, xb[(size_t)c*DD + k]);
      s_newm[k] = v;
      const float p = wredsum(v*v);
      if (lane == 0) s_nm2part[wu] = p;
    }
    {
      const float* xg = xb + (size_t)gu*8*DD;
      float acc[8] = {0,0,0,0,0,0,0,0};
      const int k0 = hu*128;
#pragma unroll 4
      for (int kk = 0; kk < 128; ++kk){
        const int k = k0 + kk;
        const float mv = memT[k][lane];
#pragma unroll
        for (int j = 0; j < 8; ++j)
          acc[j] = fmaf(xg[(size_t)j*DD + k], mv, acc[j]);
      }
      if (hu != 0){
#pragma unroll
        for (int j = 0; j < 8; ++j) red[hu-1][gu*8+j][lane] = acc[j];
      }
      __syncthreads();
      if (hu == 0){
#pragma unroll
        for (int j = 0; j < 8; ++j){
          const int c = gu*8 + j;
          float l = acc[j] + red[0][c][lane];
          l += red[1][c][lane];
          l += red[2][c][lane];
          red[0][c][lane] = l * inv_sqrt_d;
        }
      }
      __syncthreads();
    }
    {
#pragma unroll
      for (int r = 0; r < 2; ++r){
        const int c = w*2 + r;
        const float v  = red[0][c][lane];
        const float mx = wredmax(v);
        const float e  = expf(v - mx);
        const float s  = wredsum(e);
        red[0][c][lane] = e / s;
      }
    }
    __syncthreads();
    if (wu == 0){
      float s = 0.0f;
      for (int c = 0; c < CC; ++c) s += red[0][c][lane];
      s *= (1.0f/32.0f);
      s_score[lane] = s;
      const float ent = wredsum(-log2f(s + 1e-10f) * s);
      if (lane == 0){
        const unsigned long long v =
            ((unsigned long long)(unsigned)(t+1) << 32) |
            (unsigned long long)__float_as_uint(ent);
        __hip_atomic_store(&ctl[b*2 + (t&1)], v, __ATOMIC_RELEASE, __HIP_MEMORY_SCOPE_AGENT);
      }
      if (lane < NB){
        unsigned long long vv;
        do {
          vv = __hip_atomic_load(&ctl[lane*2 + (t&1)], __ATOMIC_ACQUIRE, __HIP_MEMORY_SCOPE_AGENT);
        } while ((unsigned)(vv >> 32) != (unsigned)(t+1));
        s_entvals[lane] = __uint_as_float((unsigned)vv);
      }
    } else if (wu >= 8){
      const int idx = wu - 8;
      float an = 0.0f, ad = 0.0f;
      const int k0 = idx*64;
#pragma unroll 4
      for (int kk = 0; kk < 64; ++kk){
        const int k = k0 + kk;
        const float mv = memT[k][lane];
        const float nv = s_newm[k];
        an = fmaf(mv, mv, an);
        ad = fmaf(nv, mv, ad);
      }
      rnp[idx*MM + lane] = an;
      rdp[idx*MM + lane] = ad;
    }
    __syncthreads();
    if (wu == 0){
      if (lane == 0){
        float es = 0.0f;
        for (int i = 0; i < NB; ++i) es += s_entvals[i];
        s_take1 = ((es * (1.0f/16.0f)) > 3.0f) ? 1 : 0;
      }
    } else if (wu == 1){
      float n2 = 0.0f, dt = 0.0f, nm2 = 0.0f;
#pragma unroll
      for (int i = 0; i < 8; ++i){ n2 += rnp[i*MM+lane]; dt += rdp[i*MM+lane]; }
#pragma unroll
      for (int i = 0; i < 8; ++i) nm2 += s_nm2part[i];
      float sim = dt / (sqrtf(nm2 + 1e-8f) * sqrtf(n2 + 1e-8f));
      int idx = lane;
#pragma unroll
      for (int o = 32; o > 0; o >>= 1){
        const float ov = __shfl_xor(sim, o);
        const int   oi = __shfl_xor(idx, o);
        if (ov > sim || (ov == sim && oi < idx)){ sim = ov; idx = oi; }
      }
      if (lane == 0) s_idx2 = idx;
    } else if (wu == 2){
      float q = (s_sc[lane] + s_score[lane]) / (s_fr[lane] + 1.0f);
      int idx = lane;
#pragma unroll
      for (int o = 32; o > 0; o >>= 1){
        const float ov = __shfl_xor(q, o);
        const int   oi = __shfl_xor(idx, o);
        if (ov < q || (ov == q && oi < idx)){ q = ov; idx = oi; }
      }
      if (lane == 0) s_idx1 = idx;
    }
    __syncthreads();
    if (s_take1){
      if (wu < 8){
        const int k = wu*64 + lane;
        memT[k][s_idx1] = s_newm[k];
      } else if (wu == 8){
        float ns = s_sc[lane] + s_score[lane];
        float nf = s_fr[lane] + 1.0f;
        if (lane == s_idx1){ ns = 0.0f; nf = 1.0f; }
        s_sc[lane] = ns; s_fr[lane] = nf;
      }
    } else {
      if (wu < 8){
        const int k = wu*64 + lane;
        const float mv = memT[k][s_idx2];
        memT[k][s_idx2] = mv + (0.7f*s_newm[k] - 0.7f*mv);
      }
    }
    __syncthreads();
  }

  if (tid == 0){
    __hip_atomic_store(&ctl[b*2], (unsigned long long)0xD00Du << 32,
                       __ATOMIC_RELEASE, __HIP_MEMORY_SCOPE_AGENT);
  }
  if (tid < NB){
    unsigned long long vv;
    do {
      vv = __hip_atomic_load(&ctl[tid*2], __ATOMIC_ACQUIRE, __HIP_MEMORY_SCOPE_AGENT);
    } while ((unsigned)(vv >> 32) != 0xD00Du);
  }
  __syncthreads();

  {
    const int m  = tid >> 4;
    const int kc = tid & 15;
    float* dst = out + ((size_t)b*MM + m)*DD;
#pragma unroll 4
    for (int i = 0; i < 32; ++i){ const int k = kc + i*16; dst[k] = memT[k][m]; }
  }
}

extern "C" void kernel_launch(void* const* d_in, const int* in_sizes, int n_in,
                              void* d_out, int out_size, void* d_ws, size_t ws_size,
                              hipStream_t stream)
{
  const float* x  = (const float*)d_in[0];
  const float* mi = (const float*)d_in[1];
  float* out = (float*)d_out;
  if (ws_size >= (size_t)WS_TOTAL_BYTES){
    float* ws = (float*)d_ws;
    hipLaunchKernelGGL(k1_newm, dim3(NB*NCH), dim3(256), 0, stream, x, ws);
    hipLaunchKernelGGL(k2_gx,   dim3(NB, 3, 16), dim3(1024), 0, stream, x, mi, ws);
    hipLaunchKernelGGL(k3_scan, dim3(NB), dim3(1024), 0, stream, mi, ws, out);
  } else {
    hipLaunchKernelGGL(membank_kernel, dim3(NB), dim3(1024), 0, stream, x, mi, out);
  }
}

// Round 3
// 838.968 us; speedup vs baseline: 2.6363x; 1.2193x over previous
//
#include <hip/hip_runtime.h>
#include <stdint.h>

#define NB 16      // batch
#define TT 4096    // seq len
#define DD 512     // dim
#define CC 32      // chunk size
#define MM 64      // mem slots
#define NCH 128    // number of chunks
#define NSRC 192   // 64 init + 128 newm sources
#define ROWW 36    // Gx row stride floats: 32 logits + 1 NN + 3 pad
#define TOTROWS 16320  // sum_{t=0}^{127} (64+t)
#define KS 32      // k-step for k2 GEMM

// ws float-offsets
#define WS_NEWM 0
#define WS_NN2  (NB*NCH*DD)                 // 1,048,576
#define WS_GX   (WS_NN2 + NB*NCH)           // 1,050,624
#define WS_CTL  (WS_GX + (size_t)NB*TOTROWS*ROWW)   // 10,450,944 (floats)
#define WS_TOTAL_BYTES (WS_CTL*4 + (size_t)NB*16*8) // ~41.8 MB + 2 KB

__device__ __forceinline__ float wredsum(float v){
#pragma unroll
  for (int o = 32; o > 0; o >>= 1) v += __shfl_xor(v, o);
  return v;
}
__device__ __forceinline__ float wredmax(float v){
#pragma unroll
  for (int o = 32; o > 0; o >>= 1) v = fmaxf(v, __shfl_xor(v, o));
  return v;
}

// ======================= K1: maxpool new_m + ||new_m||^2 =======================
__global__ __launch_bounds__(256)
void k1_newm(const float* __restrict__ x, float* __restrict__ ws)
{
  __shared__ float part[4];
  const int bid = blockIdx.x;
  const int b = bid >> 7, t = bid & 127;
  const int tid = threadIdx.x;
  const float* xb = x + ((size_t)b*TT + (size_t)t*CC)*DD;
  const int k0 = tid*2;
  float v0 = -INFINITY, v1 = -INFINITY;
#pragma unroll
  for (int c = 0; c < CC; ++c){
    const float2 xv = *(const float2*)(xb + (size_t)c*DD + k0);
    v0 = fmaxf(v0, xv.x); v1 = fmaxf(v1, xv.y);
  }
  float* nm = ws + WS_NEWM + ((size_t)b*NCH + t)*DD;
  nm[k0] = v0; nm[k0+1] = v1;
  float p = wredsum(v0*v0 + v1*v1);
  if ((tid & 63) == 0) part[tid >> 6] = p;
  __syncthreads();
  if (tid == 0) ws[WS_NN2 + (size_t)b*NCH + t] = part[0]+part[1]+part[2]+part[3];
}

// ======================= K2: tiled GEMM  G = X . S^T  =======================
// grid (b, tg=0..31). Block: 512 thr. Tile: 128 tokens (4 chunks) x 192 rows, K=512.
// Writes Gx[t][row][c] (c contiguous) scaled by 1/sqrt(D); row valid iff row < 64+t.
__global__ __launch_bounds__(512)
void k2_gemm(const float* __restrict__ x, const float* __restrict__ mem_init,
             float* __restrict__ ws)
{
  __shared__ float Xs[KS][128];      // [k][token] 16 KB
  __shared__ float Ss[KS][NSRC];     // [k][row]   24 KB

  const int b  = blockIdx.x;
  const int tg = blockIdx.y;
  const int tid = threadIdx.x;
  const int rowlim = min(NSRC, 68 + 4*tg);    // rows ever valid in this t-range
  const int T0 = tg*128;

  const int ot = tid & 15;           // token octet (8 tokens)
  const int rs = tid >> 4;           // row sextet (6 rows), 0..31
  const bool active = (rs*6 < rowlim);

  float acc[6][8];
#pragma unroll
  for (int j = 0; j < 6; ++j)
#pragma unroll
    for (int i = 0; i < 8; ++i) acc[j][i] = 0.0f;

  const float* xb    = x + ((size_t)b*TT + T0)*DD;
  const float* nmarr = ws + WS_NEWM + (size_t)b*NCH*DD;

  // staging roles
  const int xtok = tid >> 2;         // 0..127
  const int xkq  = tid & 3;          // k sub-octet
  const int srow = tid >> 1;         // 0..255 (only tid<384 stage S)
  const int shalf= tid & 1;
  const float* srcrow = nullptr;
  if (tid < 384 && srow < rowlim)
    srcrow = (srow < MM) ? (mem_init + ((size_t)b*MM + srow)*DD)
                         : (nmarr + (size_t)(srow - MM)*DD);

  for (int ks = 0; ks < DD/KS; ++ks){
    const int k0 = ks*KS;
    // ---- stage X (transposed) ----
    {
      const float* p = xb + (size_t)xtok*DD + k0 + xkq*8;
      const float4 a  = *(const float4*)p;
      const float4 c4 = *(const float4*)(p + 4);
      const int kb = xkq*8;
      Xs[kb+0][xtok]=a.x;  Xs[kb+1][xtok]=a.y;  Xs[kb+2][xtok]=a.z;  Xs[kb+3][xtok]=a.w;
      Xs[kb+4][xtok]=c4.x; Xs[kb+5][xtok]=c4.y; Xs[kb+6][xtok]=c4.z; Xs[kb+7][xtok]=c4.w;
    }
    // ---- stage S (transposed) ----
    if (srcrow){
      const float* p = srcrow + k0 + shalf*16;
#pragma unroll
      for (int q = 0; q < 4; ++q){
        const float4 a = *(const float4*)(p + q*4);
        const int kb = shalf*16 + q*4;
        Ss[kb+0][srow]=a.x; Ss[kb+1][srow]=a.y; Ss[kb+2][srow]=a.z; Ss[kb+3][srow]=a.w;
      }
    }
    __syncthreads();
    // ---- compute ----
    if (active){
#pragma unroll
      for (int k = 0; k < KS; ++k){
        const float4 x0 = *(const float4*)&Xs[k][ot*8];
        const float4 x1 = *(const float4*)&Xs[k][ot*8 + 4];
        const float2 r0 = *(const float2*)&Ss[k][rs*6];
        const float2 r1 = *(const float2*)&Ss[k][rs*6 + 2];
        const float2 r2 = *(const float2*)&Ss[k][rs*6 + 4];
        const float xv[8] = {x0.x,x0.y,x0.z,x0.w,x1.x,x1.y,x1.z,x1.w};
        const float rv[6] = {r0.x,r0.y,r1.x,r1.y,r2.x,r2.y};
#pragma unroll
        for (int j = 0; j < 6; ++j)
#pragma unroll
          for (int i = 0; i < 8; ++i)
            acc[j][i] = fmaf(rv[j], xv[i], acc[j][i]);
      }
    }
    __syncthreads();
  }

  // ---- store (Gx layout [t][row][c], c contiguous) ----
  const float inv_sqrt_d = 1.0f / sqrtf((float)DD);
  const int t  = tg*4 + (ot >> 2);
  const int c0 = (ot & 3)*8;
  float* gbase = ws + WS_GX + ((size_t)b*TOTROWS + (size_t)(64*t + (t*(t-1))/2))*ROWW;
#pragma unroll
  for (int j = 0; j < 6; ++j){
    const int row = rs*6 + j;
    if (row < 64 + t){
      float* g = gbase + (size_t)row*ROWW + c0;
      float4 o0 = {acc[j][0]*inv_sqrt_d, acc[j][1]*inv_sqrt_d,
                   acc[j][2]*inv_sqrt_d, acc[j][3]*inv_sqrt_d};
      float4 o1 = {acc[j][4]*inv_sqrt_d, acc[j][5]*inv_sqrt_d,
                   acc[j][6]*inv_sqrt_d, acc[j][7]*inv_sqrt_d};
      *(float4*)g = o0;
      *(float4*)(g + 4) = o1;
    }
  }
}

// ======================= K2b: NN column  grow[32] = newm_t . src_row =======================
__global__ __launch_bounds__(256)
void k2_nn(const float* __restrict__ mem_init, float* __restrict__ ws)
{
  __shared__ float nm[DD];
  const int b = blockIdx.x, t = blockIdx.y;
  const int tid = threadIdx.x, lane = tid & 63, w = tid >> 6;
  const float* nmarr = ws + WS_NEWM + (size_t)b*NCH*DD;
  {
    const float2 v = *(const float2*)(nmarr + (size_t)t*DD + tid*2);
    nm[tid*2] = v.x; nm[tid*2+1] = v.y;
  }
  __syncthreads();
  const float4 na = *(const float4*)(nm + lane*8);
  const float4 nc = *(const float4*)(nm + lane*8 + 4);
  const int nrows = MM + t;
  float* gbase = ws + WS_GX + ((size_t)b*TOTROWS + (size_t)(64*t + (t*(t-1))/2))*ROWW;
  for (int r = w; r < nrows; r += 4){
    const float* src = (r < MM) ? (mem_init + ((size_t)b*MM + r)*DD)
                                : (nmarr + (size_t)(r - MM)*DD);
    const float4 a  = *(const float4*)(src + lane*8);
    const float4 c4 = *(const float4*)(src + lane*8 + 4);
    float d = a.x*na.x + a.y*na.y + a.z*na.z + a.w*na.w
            + c4.x*nc.x + c4.y*nc.y + c4.z*nc.z + c4.w*nc.w;
    d = wredsum(d);
    if (lane == 0) gbase[(size_t)r*ROWW + 32] = d;
  }
}

// ======================= K3: sequential scan in coefficient space =======================
__global__ __launch_bounds__(1024)
void k3_scan(const float* __restrict__ mem_init, float* __restrict__ ws,
             float* __restrict__ out)
{
  __shared__ float red0[CC*65];        // logits [c][m] stride 65
  __shared__ float dense[MM][NSRC];    // dense coef rows (complex slots only)
  __shared__ float s_spart[16][MM];    // per-wave prob partial sums
  __shared__ float s_score[MM], s_sc[MM], s_fr[MM], s_n2[MM], s_simdot[MM];
  __shared__ int   s_srcRow[MM], s_isC[MM];
  __shared__ float s_entvals[NB];
  __shared__ int   s_take1, s_idx1, s_idx2, s_chg;

  const int tid  = threadIdx.x;
  const int lane = tid & 63;
  const int w    = tid >> 6;
  const int b    = blockIdx.x;
  const int wu   = __builtin_amdgcn_readfirstlane(w);

  const float* newmarr = ws + WS_NEWM;
  const float* nn2arr  = ws + WS_NN2;
  const float* gx      = ws + WS_GX;
  unsigned long long* ctl = (unsigned long long*)(ws + WS_CTL);  // 128B stride per batch

  if (tid < MM){ s_sc[tid] = 0.0f; s_fr[tid] = 0.0f; s_srcRow[tid] = tid; s_isC[tid] = 0; }
  if (tid == 0) s_chg = -1;
#pragma unroll
  for (int it = 0; it < 4; ++it){       // init norms ||mem_init[m]||^2
    const int m0 = wu + it*16;
    const float* src = mem_init + ((size_t)b*MM + m0)*DD;
    const float4 a  = *(const float4*)(src + lane*8);
    const float4 c4 = *(const float4*)(src + lane*8 + 4);
    float p = a.x*a.x + a.y*a.y + a.z*a.z + a.w*a.w
            + c4.x*c4.x + c4.y*c4.y + c4.z*c4.z + c4.w*c4.w;
    p = wredsum(p);
    if (lane == 0) s_n2[m0] = p;
  }
  __syncthreads();

  const int  m   = tid >> 4;
  const int  c2  = (tid & 15)*2;
  const bool sdl = ((tid & 15) == 0);
  float pv0 = 0.0f, pv1 = 0.0f, psd = 0.0f;   // prefetched Gx values for t+1

  for (int t = 0; t < NCH; ++t){
    const float nn2_t = nn2arr[(size_t)b*NCH + t];
    const float* gxb = gx + ((size_t)b*TOTROWS + (size_t)(64*t + (t*(t-1))/2))*ROWW;

    // ---- Ph1: logits [32c][64m] + sim-dot ----
    {
      float v0, v1;
      if (!s_isC[m]){
        if (t == 0 || m == s_chg){
          const float* grow = gxb + (size_t)s_srcRow[m]*ROWW;
          const float2 p = *(const float2*)(grow + c2);
          v0 = p.x; v1 = p.y;
          if (sdl) s_simdot[m] = grow[32];
        } else {
          v0 = pv0; v1 = pv1;
          if (sdl) s_simdot[m] = psd;
        }
      } else {
        v0 = 0.0f; v1 = 0.0f; float sd = 0.0f;
        const int ns = 64 + t;
        for (int s = 0; s < ns; ++s){
          const float co = dense[m][s];
          if (co != 0.0f){
            const float* grow = gxb + (size_t)s*ROWW;
            v0 = fmaf(co, grow[c2],   v0);
            v1 = fmaf(co, grow[c2+1], v1);
            if (sdl) sd = fmaf(co, grow[32], sd);
          }
        }
        if (sdl) s_simdot[m] = sd;
      }
      red0[c2*65 + m]     = v0;
      red0[(c2+1)*65 + m] = v1;
    }
    __syncthreads();

    // ---- Ph2: softmax rows 2w,2w+1; keep only the per-lane prob partial ----
    {
      const float a0 = red0[(2*w)*65 + lane];
      const float a1 = red0[(2*w+1)*65 + lane];
      const float mx0 = wredmax(a0), mx1 = wredmax(a1);
      const float e0 = expf(a0 - mx0), e1 = expf(a1 - mx1);
      const float su0 = wredsum(e0), su1 = wredsum(e1);
      s_spart[w][lane] = e0/su0 + e1/su1;
    }
    __syncthreads();

    // ---- prefetch Gx for t+1 with current srcRow (patched next iter if slot changed) ----
    if (t+1 < NCH && !s_isC[m]){
      const float* growN = gx + ((size_t)b*TOTROWS + (size_t)(64*(t+1) + ((t+1)*t)/2))*ROWW
                              + (size_t)s_srcRow[m]*ROWW;
      const float2 p = *(const float2*)(growN + c2);
      pv0 = p.x; pv1 = p.y;
      if (sdl) psd = growN[32];
    }

    // ---- Ph3: wave0 score/entropy/publish/argmin/spin/decide; wave1 sim argmax ----
    if (wu == 0){
      float s = 0.0f;
#pragma unroll
      for (int i = 0; i < 16; ++i) s += s_spart[i][lane];
      s *= (1.0f/32.0f);
      s_score[lane] = s;
      const float ent = wredsum(-log2f(s + 1e-10f) * s);
      if (lane == 0){
        const unsigned long long v =
            ((unsigned long long)(unsigned)(t+1) << 32) |
            (unsigned long long)__float_as_uint(ent);
        __hip_atomic_store(&ctl[b*16 + (t&1)], v, __ATOMIC_RELEASE, __HIP_MEMORY_SCOPE_AGENT);
      }
      {
        float q = (s_sc[lane] + s) / (s_fr[lane] + 1.0f);
        int idx = lane;
#pragma unroll
        for (int o = 32; o > 0; o >>= 1){
          const float ov = __shfl_xor(q, o);
          const int   oi = __shfl_xor(idx, o);
          if (ov < q || (ov == q && oi < idx)){ q = ov; idx = oi; }
        }
        if (lane == 0) s_idx1 = idx;
      }
      if (lane < NB){
        unsigned long long vv;
        do {
          vv = __hip_atomic_load(&ctl[lane*16 + (t&1)], __ATOMIC_ACQUIRE, __HIP_MEMORY_SCOPE_AGENT);
        } while ((unsigned)(vv >> 32) != (unsigned)(t+1));
        s_entvals[lane] = __uint_as_float((unsigned)vv);
      }
      if (lane == 0){
        float es = 0.0f;
        for (int i = 0; i < NB; ++i) es += s_entvals[i];
        s_take1 = ((es * (1.0f/16.0f)) > 3.0f) ? 1 : 0;   // 0.5*log2(64+1e-10) == 3.0f
      }
    } else if (wu == 1){
      float sim = s_simdot[lane] / (sqrtf(nn2_t + 1e-8f) * sqrtf(s_n2[lane] + 1e-8f));
      int idx = lane;
#pragma unroll
      for (int o = 32; o > 0; o >>= 1){
        const float ov = __shfl_xor(sim, o);
        const int   oi = __shfl_xor(idx, o);
        if (ov > sim || (ov == sim && oi < idx)){ sim = ov; idx = oi; }
      }
      if (lane == 0) s_idx2 = idx;
    }
    __syncthreads();

    // ---- Ph5: apply update (merged) ----
    if (s_take1){
      if (tid < MM){
        float ns = s_sc[tid] + s_score[tid];
        float nf = s_fr[tid] + 1.0f;
        if (tid == s_idx1){ ns = 0.0f; nf = 1.0f; }
        s_sc[tid] = ns; s_fr[tid] = nf;
      }
      if (tid == 512){
        const int rr = s_idx1;
        s_isC[rr] = 0; s_srcRow[rr] = 64 + t; s_n2[rr] = nn2_t; s_chg = rr;
      }
    } else {
      const int i = s_idx2;
      const int oldC = s_isC[i];
      const int oldR = s_srcRow[i];
      __syncthreads();   // uniform branch: all threads take same path
      if (tid < NSRC){
        float val = oldC ? 0.3f*dense[i][tid] : ((tid == oldR) ? 0.3f : 0.0f);
        if (tid == 64 + t) val += 0.7f;
        dense[i][tid] = val;
      }
      if (tid == 512){
        s_isC[i] = 1;
        s_n2[i] = 0.09f*s_n2[i] + 0.42f*s_simdot[i] + 0.49f*nn2_t;
        s_chg = i;
      }
    }
    __syncthreads();
  }

  // ---- reconstruction: out[b][m][:] from basis vectors ----
#pragma unroll
  for (int it = 0; it < 4; ++it){
    const int mo = wu + it*16;
    const int k0 = lane*8;
    float o8[8];
    if (!s_isC[mo]){
      const int row = s_srcRow[mo];
      const float* vec = (row < MM) ? (mem_init + ((size_t)b*MM + row)*DD)
                                    : (newmarr + ((size_t)b*NCH + (row - MM))*DD);
#pragma unroll
      for (int j = 0; j < 8; ++j) o8[j] = vec[k0 + j];
    } else {
#pragma unroll
      for (int j = 0; j < 8; ++j) o8[j] = 0.0f;
      for (int s = 0; s < NSRC; ++s){
        const float co = dense[mo][s];
        if (co != 0.0f){
          const float* vec = (s < MM) ? (mem_init + ((size_t)b*MM + s)*DD)
                                      : (newmarr + ((size_t)b*NCH + (s - MM))*DD);
#pragma unroll
          for (int j = 0; j < 8; ++j) o8[j] = fmaf(co, vec[k0 + j], o8[j]);
        }
      }
    }
    float* dst = out + ((size_t)b*MM + mo)*DD + k0;
#pragma unroll
    for (int j = 0; j < 8; ++j) dst[j] = o8[j];
  }
}

extern "C" void kernel_launch(void* const* d_in, const int* in_sizes, int n_in,
                              void* d_out, int out_size, void* d_ws, size_t ws_size,
                              hipStream_t stream)
{
  const float* x  = (const float*)d_in[0];
  const float* mi = (const float*)d_in[1];
  float* out = (float*)d_out;
  float* ws  = (float*)d_ws;
  hipLaunchKernelGGL(k1_newm, dim3(NB*NCH), dim3(256), 0, stream, x, ws);
  hipLaunchKernelGGL(k2_gemm, dim3(NB, 32), dim3(512), 0, stream, x, mi, ws);
  hipLaunchKernelGGL(k2_nn,   dim3(NB, NCH), dim3(256), 0, stream, mi, ws);
  hipLaunchKernelGGL(k3_scan, dim3(NB), dim3(1024), 0, stream, mi, ws, out);
}